// Round 2
// baseline (10468.634 us; speedup 1.0000x reference)
//
#include <hip/hip_runtime.h>
#include <hip/hip_bf16.h>

typedef __bf16 bf16_t;
typedef bf16_t bf16x8 __attribute__((ext_vector_type(8)));
typedef bf16_t bf16x4 __attribute__((ext_vector_type(4)));
typedef float  f32x4  __attribute__((ext_vector_type(4)));

constexpr int Bb = 64;
constexpr int T  = 512;
constexpr int D  = 512;
constexpr int H  = 512;
constexpr int M1 = Bb * T;     // 32768 rows of zi
constexpr int N1 = 3 * H;      // 1536 gate columns

#define LDK 72   // padded LDS row stride (bf16 elems): 64+8 keeps 16B align, breaks conflicts

// ---------------------------------------------------------------------------
// Convert w_hh (fp32 [1536][512]) -> bf16, both directions.
// ---------------------------------------------------------------------------
__global__ __launch_bounds__(256) void conv_whh(
    const float* __restrict__ wf, const float* __restrict__ wb,
    bf16_t* __restrict__ of, bf16_t* __restrict__ ob)
{
    const float* __restrict__ s = blockIdx.y ? wb : wf;
    bf16_t* __restrict__ d = blockIdx.y ? ob : of;
    int i = (blockIdx.x * 256 + threadIdx.x) * 4;
    float4 v = *(const float4*)&s[i];
    bf16x4 t = { (bf16_t)v.x, (bf16_t)v.y, (bf16_t)v.z, (bf16_t)v.w };
    *(bf16x4*)&d[i] = t;
}

// ---------------------------------------------------------------------------
// Phase 1: zi[dir] = x @ w_ih[dir]^T + b_ih   (fp32 in, bf16 MFMA, ZT out)
// 128x128 tile, BK=64, 4 waves each 64x64 via 16x16x32 bf16 MFMA.
// fp32 -> bf16 conversion fused into LDS staging.
// ---------------------------------------------------------------------------
template <typename ZT>
__global__ __launch_bounds__(256) void zi_gemm(
    const float* __restrict__ x,
    const float* __restrict__ w_fw, const float* __restrict__ w_bw,
    const float* __restrict__ b_fw, const float* __restrict__ b_bw,
    ZT* __restrict__ zi)
{
    const int dir = blockIdx.z;
    const float* __restrict__ w    = dir ? w_bw : w_fw;
    const float* __restrict__ bias = dir ? b_bw : b_fw;
    ZT* __restrict__ out = zi + (size_t)dir * M1 * N1;

    const int m0 = blockIdx.x * 128;
    const int n0 = blockIdx.y * 128;

    __shared__ bf16_t As[128 * LDK];
    __shared__ bf16_t Bs[128 * LDK];

    const int tid  = threadIdx.x;
    const int lane = tid & 63;
    const int wave = tid >> 6;
    const int wm = (wave >> 1) * 64;
    const int wn = (wave & 1) * 64;
    const int q   = lane >> 4;
    const int l16 = lane & 15;

    f32x4 acc[4][4] = {};

    for (int kt = 0; kt < D; kt += 64) {
#pragma unroll
        for (int p = 0; p < 4; ++p) {
            int idx = tid + p * 256;
            int row = idx >> 3;
            int seg = idx & 7;
            const float* sa = &x[(size_t)(m0 + row) * D + kt + seg * 8];
            const float* sb = &w[(size_t)(n0 + row) * D + kt + seg * 8];
            float4 a0 = *(const float4*)sa;
            float4 a1 = *(const float4*)(sa + 4);
            float4 b0 = *(const float4*)sb;
            float4 b1 = *(const float4*)(sb + 4);
            bf16x8 ta = { (bf16_t)a0.x, (bf16_t)a0.y, (bf16_t)a0.z, (bf16_t)a0.w,
                          (bf16_t)a1.x, (bf16_t)a1.y, (bf16_t)a1.z, (bf16_t)a1.w };
            bf16x8 tb = { (bf16_t)b0.x, (bf16_t)b0.y, (bf16_t)b0.z, (bf16_t)b0.w,
                          (bf16_t)b1.x, (bf16_t)b1.y, (bf16_t)b1.z, (bf16_t)b1.w };
            *(bf16x8*)&As[row * LDK + seg * 8] = ta;
            *(bf16x8*)&Bs[row * LDK + seg * 8] = tb;
        }
        __syncthreads();
#pragma unroll
        for (int kk = 0; kk < 64; kk += 32) {
            bf16x8 afr[4], bfr[4];
#pragma unroll
            for (int i = 0; i < 4; ++i)
                afr[i] = *(const bf16x8*)&As[(wm + i * 16 + l16) * LDK + kk + q * 8];
#pragma unroll
            for (int j = 0; j < 4; ++j)
                bfr[j] = *(const bf16x8*)&Bs[(wn + j * 16 + l16) * LDK + kk + q * 8];
#pragma unroll
            for (int i = 0; i < 4; ++i)
#pragma unroll
                for (int j = 0; j < 4; ++j)
                    acc[i][j] = __builtin_amdgcn_mfma_f32_16x16x32_bf16(
                        afr[i], bfr[j], acc[i][j], 0, 0, 0);
        }
        __syncthreads();
    }

    // C/D layout: col = lane&15, row = (lane>>4)*4 + reg
#pragma unroll
    for (int i = 0; i < 4; ++i) {
        int grow = m0 + wm + i * 16 + q * 4;
#pragma unroll
        for (int j = 0; j < 4; ++j) {
            int gcol = n0 + wn + j * 16 + l16;
            float bia = bias[gcol];
#pragma unroll
            for (int r = 0; r < 4; ++r) {
                float v = acc[i][j][r] + bia;
                out[(size_t)(grow + r) * N1 + gcol] = (ZT)v;
            }
        }
    }
}

// ---------------------------------------------------------------------------
// Phase 2: one launch per time step, both directions (blockIdx.z).
// Grid (8, 2, 2): bx = 64-col chunk of H, by = 32-row batch chunk.
// Each wave owns 16 h-columns; zh via MFMA (bf16 h, bf16 whh), gates fp32.
// ---------------------------------------------------------------------------
template <typename ZT>
__global__ __launch_bounds__(256) void gru_step(
    const ZT* __restrict__ zi,            // [2][M1][N1]
    const bf16_t* __restrict__ whh16,     // [2][1536][512] converted
    const float* __restrict__ bhh_fw,
    const float* __restrict__ bhh_bw,
    float* __restrict__ hf32,             // [2 dir][2 buf][64][512]
    bf16_t* __restrict__ hb16,            // [2 dir][2 buf][64][512]
    float* __restrict__ out,              // [B][T][2H] fp32
    float* __restrict__ hlast,            // [2][64][512] (tail of d_out)
    int s)
{
    const int dir = blockIdx.z;
    const int t = dir ? (T - 1 - s) : s;
    const bf16_t* __restrict__ whh = whh16 + (size_t)dir * N1 * H;
    const float* __restrict__ bhh = dir ? bhh_bw : bhh_fw;
    const ZT* __restrict__ zid = zi + (size_t)dir * M1 * N1;

    const float*  hprev32 = hf32 + ((size_t)dir * 2 + (s & 1)) * Bb * H;
    float*        hnext32 = hf32 + ((size_t)dir * 2 + ((s + 1) & 1)) * Bb * H;
    const bf16_t* hprev16 = hb16 + ((size_t)dir * 2 + (s & 1)) * Bb * H;
    bf16_t*       hnext16 = hb16 + ((size_t)dir * 2 + ((s + 1) & 1)) * Bb * H;

    const int lane = threadIdx.x & 63;
    const int wave = threadIdx.x >> 6;
    const int q   = lane >> 4;
    const int l16 = lane & 15;
    const int c0  = blockIdx.x * 64 + wave * 16;
    const int m0  = blockIdx.y * 32;

    f32x4 acc[3][2] = {};

#pragma unroll 4
    for (int kt = 0; kt < H; kt += 32) {
        bf16x8 afr[2], bfr[3];
#pragma unroll
        for (int i = 0; i < 2; ++i)
            afr[i] = *(const bf16x8*)&hprev16[(size_t)(m0 + i * 16 + l16) * H + kt + q * 8];
#pragma unroll
        for (int g = 0; g < 3; ++g)
            bfr[g] = *(const bf16x8*)&whh[(size_t)(g * H + c0 + l16) * H + kt + q * 8];
#pragma unroll
        for (int g = 0; g < 3; ++g)
#pragma unroll
            for (int i = 0; i < 2; ++i)
                acc[g][i] = __builtin_amdgcn_mfma_f32_16x16x32_bf16(
                    afr[i], bfr[g], acc[g][i], 0, 0, 0);
    }

    const int c = c0 + l16;
    const float bh_r = bhh[c];
    const float bh_z = bhh[H + c];
    const float bh_n = bhh[2 * H + c];

#pragma unroll
    for (int i = 0; i < 2; ++i) {
#pragma unroll
        for (int r = 0; r < 4; ++r) {
            int row = m0 + i * 16 + q * 4 + r;   // batch index
            size_t zbase = ((size_t)row * T + t) * N1;
            float zi_r = (float)zid[zbase + c];
            float zi_z = (float)zid[zbase + H + c];
            float zi_n = (float)zid[zbase + 2 * H + c];
            float zh_r = acc[0][i][r] + bh_r;
            float zh_z = acc[1][i][r] + bh_z;
            float zh_n = acc[2][i][r] + bh_n;
            float rg = 1.f / (1.f + __expf(-(zi_r + zh_r)));
            float zg = 1.f / (1.f + __expf(-(zi_z + zh_z)));
            float ng = tanhf(zi_n + rg * zh_n);
            float hp = hprev32[(size_t)row * H + c];
            float hn = (1.f - zg) * ng + zg * hp;
            hnext32[(size_t)row * H + c] = hn;
            hnext16[(size_t)row * H + c] = (bf16_t)hn;
            out[((size_t)row * T + t) * (2 * H) + dir * H + c] = hn;
            if (s == T - 1)
                hlast[((size_t)dir * Bb + row) * H + c] = hn;
        }
    }
}

// ---------------------------------------------------------------------------
extern "C" void kernel_launch(void* const* d_in, const int* in_sizes, int n_in,
                              void* d_out, int out_size, void* d_ws, size_t ws_size,
                              hipStream_t stream)
{
    const float* x       = (const float*)d_in[0];
    const float* w_ih_fw = (const float*)d_in[1];
    const float* w_hh_fw = (const float*)d_in[2];
    const float* b_ih_fw = (const float*)d_in[3];
    const float* b_hh_fw = (const float*)d_in[4];
    const float* w_ih_bw = (const float*)d_in[5];
    const float* w_hh_bw = (const float*)d_in[6];
    const float* b_ih_bw = (const float*)d_in[7];
    const float* b_hh_bw = (const float*)d_in[8];

    float* out = (float*)d_out;
    float* hlast = out + (size_t)Bb * T * 2 * H;

    char* ws = (char*)d_ws;
    float*  hf32  = (float*)ws;                      // 524288 B
    bf16_t* hb16  = (bf16_t*)(ws + 524288);          // 262144 B
    bf16_t* whh16 = (bf16_t*)(ws + 786432);          // 2*1536*512*2 = 3145728 B
    void*   zi    = (void*)(ws + (4u << 20));        // 4 MiB offset

    const size_t need_f32 = (4ull << 20) + 2ull * M1 * N1 * sizeof(float);
    const bool use_f32 = (ws_size >= need_f32);

    // zero h ping-pong buffers (ws is re-poisoned 0xAA before every launch)
    hipMemsetAsync(d_ws, 0, 786432, stream);

    conv_whh<<<dim3(N1 * H / (256 * 4), 2), 256, 0, stream>>>(
        w_hh_fw, w_hh_bw, whh16, whh16 + (size_t)N1 * H);

    dim3 g1(M1 / 128, N1 / 128, 2);   // 256 x 12 x 2
    dim3 g2(H / 64, Bb / 32, 2);      // 8 x 2 x 2

    if (use_f32) {
        zi_gemm<float><<<g1, 256, 0, stream>>>(
            x, w_ih_fw, w_ih_bw, b_ih_fw, b_ih_bw, (float*)zi);
        for (int s = 0; s < T; ++s)
            gru_step<float><<<g2, 256, 0, stream>>>(
                (const float*)zi, whh16, b_hh_fw, b_hh_bw,
                hf32, hb16, out, hlast, s);
    } else {
        zi_gemm<bf16_t><<<g1, 256, 0, stream>>>(
            x, w_ih_fw, w_ih_bw, b_ih_fw, b_ih_bw, (bf16_t*)zi);
        for (int s = 0; s < T; ++s)
            gru_step<bf16_t><<<g2, 256, 0, stream>>>(
                (const bf16_t*)zi, whh16, b_hh_fw, b_hh_bw,
                hf32, hb16, out, hlast, s);
    }
}

// Round 4
// 4684.830 us; speedup vs baseline: 2.2346x; 2.2346x over previous
//
#include <hip/hip_runtime.h>
#include <hip/hip_bf16.h>

typedef __bf16 bf16_t;
typedef bf16_t bf16x8 __attribute__((ext_vector_type(8)));
typedef float  f32x4  __attribute__((ext_vector_type(4)));

constexpr int Bb = 64;
constexpr int T  = 512;
constexpr int D  = 512;
constexpr int H  = 512;
constexpr int M1 = Bb * T;     // 32768 rows of zi
constexpr int N1 = 3 * H;      // 1536 gate columns

#define LDK 72   // padded LDS row stride (bf16 elems)

// ---------------------------------------------------------------------------
// Phase 1: zi[dir] = x @ w_ih[dir]^T + b_ih   (fp32 in, bf16 MFMA, ZT out)
// 128x128 tile, BK=64, 4 waves each 64x64 via 16x16x32 bf16 MFMA.
// ---------------------------------------------------------------------------
template <typename ZT>
__global__ __launch_bounds__(256) void zi_gemm(
    const float* __restrict__ x,
    const float* __restrict__ w_fw, const float* __restrict__ w_bw,
    const float* __restrict__ b_fw, const float* __restrict__ b_bw,
    ZT* __restrict__ zi)
{
    const int dir = blockIdx.z;
    const float* __restrict__ w    = dir ? w_bw : w_fw;
    const float* __restrict__ bias = dir ? b_bw : b_fw;
    ZT* __restrict__ out = zi + (size_t)dir * M1 * N1;

    const int m0 = blockIdx.x * 128;
    const int n0 = blockIdx.y * 128;

    __shared__ bf16_t As[128 * LDK];
    __shared__ bf16_t Bs[128 * LDK];

    const int tid  = threadIdx.x;
    const int lane = tid & 63;
    const int wave = tid >> 6;
    const int wm = (wave >> 1) * 64;
    const int wn = (wave & 1) * 64;
    const int q   = lane >> 4;
    const int l16 = lane & 15;

    f32x4 acc[4][4] = {};

    for (int kt = 0; kt < D; kt += 64) {
#pragma unroll
        for (int p = 0; p < 4; ++p) {
            int idx = tid + p * 256;
            int row = idx >> 3;
            int seg = idx & 7;
            const float* sa = &x[(size_t)(m0 + row) * D + kt + seg * 8];
            const float* sb = &w[(size_t)(n0 + row) * D + kt + seg * 8];
            float4 a0 = *(const float4*)sa;
            float4 a1 = *(const float4*)(sa + 4);
            float4 b0 = *(const float4*)sb;
            float4 b1 = *(const float4*)(sb + 4);
            bf16x8 ta = { (bf16_t)a0.x, (bf16_t)a0.y, (bf16_t)a0.z, (bf16_t)a0.w,
                          (bf16_t)a1.x, (bf16_t)a1.y, (bf16_t)a1.z, (bf16_t)a1.w };
            bf16x8 tb = { (bf16_t)b0.x, (bf16_t)b0.y, (bf16_t)b0.z, (bf16_t)b0.w,
                          (bf16_t)b1.x, (bf16_t)b1.y, (bf16_t)b1.z, (bf16_t)b1.w };
            *(bf16x8*)&As[row * LDK + seg * 8] = ta;
            *(bf16x8*)&Bs[row * LDK + seg * 8] = tb;
        }
        __syncthreads();
#pragma unroll
        for (int kk = 0; kk < 64; kk += 32) {
            bf16x8 afr[4], bfr[4];
#pragma unroll
            for (int i = 0; i < 4; ++i)
                afr[i] = *(const bf16x8*)&As[(wm + i * 16 + l16) * LDK + kk + q * 8];
#pragma unroll
            for (int j = 0; j < 4; ++j)
                bfr[j] = *(const bf16x8*)&Bs[(wn + j * 16 + l16) * LDK + kk + q * 8];
#pragma unroll
            for (int i = 0; i < 4; ++i)
#pragma unroll
                for (int j = 0; j < 4; ++j)
                    acc[i][j] = __builtin_amdgcn_mfma_f32_16x16x32_bf16(
                        afr[i], bfr[j], acc[i][j], 0, 0, 0);
        }
        __syncthreads();
    }

#pragma unroll
    for (int i = 0; i < 4; ++i) {
        int grow = m0 + wm + i * 16 + q * 4;
#pragma unroll
        for (int j = 0; j < 4; ++j) {
            int gcol = n0 + wn + j * 16 + l16;
            float bia = bias[gcol];
#pragma unroll
            for (int r = 0; r < 4; ++r) {
                float v = acc[i][j][r] + bia;
                out[(size_t)(grow + r) * N1 + gcol] = (ZT)v;
            }
        }
    }
}

// ---------------------------------------------------------------------------
// Phase 2: persistent kernel (PLAIN launch — 64 blocks <= 256 CUs, so all
// blocks are co-resident; coop launch failed silently in R3).
// Grid (32, 2): blockIdx.x = 16-col chunk of H, blockIdx.y = dir.
// Block = 4 waves, wave w owns rows [16w,16w+16) x block's 16 h-cols.
// w_hh in registers (48 bf16x8/wave, loaded once, fp32->bf16 fused).
// h fp32 state in registers; bf16 h via global ping-pong.
// Per-dir 32-block barrier: monotone counter; __threadfence() emits the
// agent-scope L2 writeback/invalidate needed across XCDs (G16).
// ---------------------------------------------------------------------------
template <typename ZT>
__global__ __launch_bounds__(256, 1) void gru_persist(
    const ZT* __restrict__ zi,            // [2][M1][N1]
    const float* __restrict__ whh_fw,     // [1536][512] fp32
    const float* __restrict__ whh_bw,
    const float* __restrict__ bhh_fw,
    const float* __restrict__ bhh_bw,
    bf16_t* __restrict__ hb16,            // [2 dir][2 buf][64][512]
    float* __restrict__ out,              // [B][T][2H]
    float* __restrict__ hlast,            // [2][64][512]
    unsigned int* __restrict__ bar)       // 2 counters, 128B apart
{
    const int dir = blockIdx.y;
    const float* __restrict__ whh = dir ? whh_bw : whh_fw;
    const float* __restrict__ bhh = dir ? bhh_bw : bhh_fw;
    const ZT* __restrict__ zid = zi + (size_t)dir * M1 * N1;
    unsigned int* cnt = bar + dir * 32;

    const int tid  = threadIdx.x;
    const int lane = tid & 63;
    const int wave = tid >> 6;
    const int q    = lane >> 4;
    const int l16  = lane & 15;
    const int c0   = blockIdx.x * 16;     // block's 16 h-cols
    const int wm   = wave * 16;           // wave's 16 batch rows
    const int c    = c0 + l16;

    // --- persistent weights: B-frag layout B[n=l16][k=q*8+j] ---
    bf16x8 wreg[3][16];
#pragma unroll
    for (int g = 0; g < 3; ++g) {
        const float* wr = &whh[(size_t)(g * H + c0 + l16) * H];
#pragma unroll
        for (int kt = 0; kt < 16; ++kt) {
            float4 a = *(const float4*)&wr[kt * 32 + q * 8];
            float4 b = *(const float4*)&wr[kt * 32 + q * 8 + 4];
            wreg[g][kt] = (bf16x8){ (bf16_t)a.x, (bf16_t)a.y, (bf16_t)a.z, (bf16_t)a.w,
                                    (bf16_t)b.x, (bf16_t)b.y, (bf16_t)b.z, (bf16_t)b.w };
        }
    }
    const float bh_r = bhh[c];
    const float bh_z = bhh[H + c];
    const float bh_n = bhh[2 * H + c];

    bf16_t* hbase16 = hb16 + (size_t)dir * 2 * Bb * H;

    // fp32 h state: thread owns rows wm+q*4+r (r=0..3), col c
    float hcur[4] = {0.f, 0.f, 0.f, 0.f};

#pragma unroll 1
    for (int s = 0; s < T; ++s) {
        const int t = dir ? (T - 1 - s) : s;
        const bf16_t* hp16 = hbase16 + (s & 1) * Bb * H;
        bf16_t*       hn16 = hbase16 + ((s + 1) & 1) * Bb * H;

        // zi prefetch (independent of h -> overlaps the MFMA chain)
        float ziv[3][4];
#pragma unroll
        for (int r = 0; r < 4; ++r) {
            int row = wm + q * 4 + r;
            size_t zb = ((size_t)row * T + t) * N1;
            ziv[0][r] = (float)zid[zb + c];
            ziv[1][r] = (float)zid[zb + H + c];
            ziv[2][r] = (float)zid[zb + 2 * H + c];
        }

        // zh = h @ whh^T : A-frag rows wm+l16, 6 acc chains (gate x K-parity)
        f32x4 acc[3][2] = {};
#pragma unroll
        for (int kc = 0; kc < 4; ++kc) {
            bf16x8 afr[4];
#pragma unroll
            for (int u = 0; u < 4; ++u)
                afr[u] = *(const bf16x8*)&hp16[(size_t)(wm + l16) * H + (kc * 4 + u) * 32 + q * 8];
#pragma unroll
            for (int u = 0; u < 4; ++u) {
                int kt = kc * 4 + u;
#pragma unroll
                for (int g = 0; g < 3; ++g)
                    acc[g][u & 1] = __builtin_amdgcn_mfma_f32_16x16x32_bf16(
                        afr[u], wreg[g][kt], acc[g][u & 1], 0, 0, 0);
            }
        }

        // gates + blend; C-layout row = q*4+r, col = l16
#pragma unroll
        for (int r = 0; r < 4; ++r) {
            int row = wm + q * 4 + r;
            float zh_r = acc[0][0][r] + acc[0][1][r] + bh_r;
            float zh_z = acc[1][0][r] + acc[1][1][r] + bh_z;
            float zh_n = acc[2][0][r] + acc[2][1][r] + bh_n;
            float rg = 1.f / (1.f + __expf(-(ziv[0][r] + zh_r)));
            float zg = 1.f / (1.f + __expf(-(ziv[1][r] + zh_z)));
            float ng = tanhf(ziv[2][r] + rg * zh_n);
            float hn = (1.f - zg) * ng + zg * hcur[r];
            hcur[r] = hn;
            hn16[(size_t)row * H + c] = (bf16_t)hn;
            out[((size_t)row * T + t) * (2 * H) + dir * H + c] = hn;
            if (s == T - 1)
                hlast[((size_t)dir * Bb + row) * H + c] = hn;
        }

        // per-dir barrier: arrive only after this block's reads+writes done
        if (s < T - 1) {
            __syncthreads();
            if (tid == 0) {
                __threadfence();   // release: L2 writeback (cross-XCD visibility)
                __hip_atomic_fetch_add(cnt, 1u, __ATOMIC_RELAXED,
                                       __HIP_MEMORY_SCOPE_AGENT);
                unsigned int target = 32u * (unsigned)(s + 1);
                while (__hip_atomic_load(cnt, __ATOMIC_RELAXED,
                                         __HIP_MEMORY_SCOPE_AGENT) < target) {
                    __builtin_amdgcn_s_sleep(1);
                }
                __threadfence();   // acquire: invalidate stale L1/L2 lines
            }
            __syncthreads();
        }
    }
}

// ---------------------------------------------------------------------------
extern "C" void kernel_launch(void* const* d_in, const int* in_sizes, int n_in,
                              void* d_out, int out_size, void* d_ws, size_t ws_size,
                              hipStream_t stream)
{
    const float* x       = (const float*)d_in[0];
    const float* w_ih_fw = (const float*)d_in[1];
    const float* w_hh_fw = (const float*)d_in[2];
    const float* b_ih_fw = (const float*)d_in[3];
    const float* b_hh_fw = (const float*)d_in[4];
    const float* w_ih_bw = (const float*)d_in[5];
    const float* w_hh_bw = (const float*)d_in[6];
    const float* b_ih_bw = (const float*)d_in[7];
    const float* b_hh_bw = (const float*)d_in[8];

    float* out   = (float*)d_out;
    float* hlast = out + (size_t)Bb * T * 2 * H;

    char* ws = (char*)d_ws;
    bf16_t*       hb16 = (bf16_t*)ws;                       // 262144 B
    unsigned int* bar  = (unsigned int*)(ws + 262144);      // 256 B
    void*         zi   = (void*)(ws + (1u << 20));          // 1 MiB offset

    const size_t need_f32 = (1ull << 20) + 2ull * M1 * N1 * sizeof(float);
    const bool use_f32 = (ws_size >= need_f32);

    // zero h ping-pong + barrier counters (ws re-poisoned before every launch)
    hipMemsetAsync(d_ws, 0, 262144 + 256, stream);

    dim3 g1(M1 / 128, N1 / 128, 2);   // 256 x 12 x 2
    dim3 g2(32, 2);                   // persistent: 32 col-chunks x 2 dirs

    if (use_f32) {
        float* zif = (float*)zi;
        zi_gemm<float><<<g1, 256, 0, stream>>>(
            x, w_ih_fw, w_ih_bw, b_ih_fw, b_ih_bw, zif);
        gru_persist<float><<<g2, 256, 0, stream>>>(
            (const float*)zif, w_hh_fw, w_hh_bw, b_hh_fw, b_hh_bw,
            hb16, out, hlast, bar);
    } else {
        bf16_t* zib = (bf16_t*)zi;
        zi_gemm<bf16_t><<<g1, 256, 0, stream>>>(
            x, w_ih_fw, w_ih_bw, b_ih_fw, b_ih_bw, zib);
        gru_persist<bf16_t><<<g2, 256, 0, stream>>>(
            (const bf16_t*)zib, w_hh_fw, w_hh_bw, b_hh_fw, b_hh_bw,
            hb16, out, hlast, bar);
    }
}